// Round 1
// baseline (162.944 us; speedup 1.0000x reference)
//
#include <hip/hip_runtime.h>
#include <math.h>

// Problem constants
constexpr int NN = 1024;   // nodes
constexpr int DD = 256;    // embedding dim
constexpr int HH = 128;    // hidden dim
constexpr float BN_EPS = 1e-5f;

// Workspace layout (in floats)
constexpr int OFF_A      = 0;                          // [1024 x 1024] adjacency
constexpr int OFF_AP     = OFF_A + NN * NN;            // [N x H] a + b1
constexpr int OFF_CP     = OFF_AP + NN * HH;           // [N x H] c
constexpr int OFF_Y      = OFF_CP + NN * HH;           // [N x H] X@Wg (scaled by dis[j] in k3)
constexpr int OFF_DIS    = OFF_Y + NN * HH;            // [N] rsqrt(deg)
constexpr int OFF_STATS  = OFF_DIS + NN;               // [256] colsum, colsumsq
constexpr int OFF_OUTPRE = OFF_STATS + 256;            // [N x H] pre-BN output
constexpr int OFF_P1     = OFF_OUTPRE + NN * HH;       // [4 dchunks][3 outs][N x H]
constexpr int OFF_P4     = OFF_P1 + 4 * 3 * NN * HH;   // [8 jchunks][N x H]

// ---------------------------------------------------------------------------
// K1: partial GEMMs  a = X@W1[:D], c = X@W1[D:], y = X@Wg   (split-K over d)
// grid (32 row-tiles, 4 d-chunks), block 256
// ---------------------------------------------------------------------------
__global__ __launch_bounds__(256) void k1_gemm_partial(
    const float* __restrict__ X, const float* __restrict__ W1,
    const float* __restrict__ Wg, float* __restrict__ P1) {
  __shared__ float xs[32 * 64];
  const int tid = threadIdx.x;
  const int i0 = blockIdx.x * 32;
  const int d0 = blockIdx.y * 64;
  for (int idx = tid; idx < 32 * 64; idx += 256) {
    int row = idx >> 6, d = idx & 63;
    xs[idx] = X[(i0 + row) * DD + d0 + d];
  }
  __syncthreads();
  const int tx = tid & 31, ty = tid >> 5;   // cols tx*4..+3, rows ty*4..+3
  float4 aA[4], aC[4], aY[4];
#pragma unroll
  for (int r = 0; r < 4; ++r) {
    aA[r] = make_float4(0.f, 0.f, 0.f, 0.f);
    aC[r] = make_float4(0.f, 0.f, 0.f, 0.f);
    aY[r] = make_float4(0.f, 0.f, 0.f, 0.f);
  }
  for (int d = 0; d < 64; ++d) {
    const int gd = d0 + d;
    const float4 wa = *(const float4*)(W1 + gd * HH + tx * 4);
    const float4 wc = *(const float4*)(W1 + (DD + gd) * HH + tx * 4);
    const float4 wg = *(const float4*)(Wg + gd * HH + tx * 4);
#pragma unroll
    for (int r = 0; r < 4; ++r) {
      const float xv = xs[(ty * 4 + r) * 64 + d];
      aA[r].x = fmaf(xv, wa.x, aA[r].x); aA[r].y = fmaf(xv, wa.y, aA[r].y);
      aA[r].z = fmaf(xv, wa.z, aA[r].z); aA[r].w = fmaf(xv, wa.w, aA[r].w);
      aC[r].x = fmaf(xv, wc.x, aC[r].x); aC[r].y = fmaf(xv, wc.y, aC[r].y);
      aC[r].z = fmaf(xv, wc.z, aC[r].z); aC[r].w = fmaf(xv, wc.w, aC[r].w);
      aY[r].x = fmaf(xv, wg.x, aY[r].x); aY[r].y = fmaf(xv, wg.y, aY[r].y);
      aY[r].z = fmaf(xv, wg.z, aY[r].z); aY[r].w = fmaf(xv, wg.w, aY[r].w);
    }
  }
  const int s = blockIdx.y;
#pragma unroll
  for (int r = 0; r < 4; ++r) {
    const int i = i0 + ty * 4 + r;
    *(float4*)(P1 + (s * 3 + 0) * (NN * HH) + i * HH + tx * 4) = aA[r];
    *(float4*)(P1 + (s * 3 + 1) * (NN * HH) + i * HH + tx * 4) = aC[r];
    *(float4*)(P1 + (s * 3 + 2) * (NN * HH) + i * HH + tx * 4) = aY[r];
  }
}

// ---------------------------------------------------------------------------
// K1b: reduce split-K partials; fold b1 into aP; zero BN-stats accumulators.
// grid 512, block 256
// ---------------------------------------------------------------------------
__global__ __launch_bounds__(256) void k1b_reduce(
    const float* __restrict__ P1, const float* __restrict__ b1,
    float* __restrict__ aP, float* __restrict__ cP, float* __restrict__ y,
    float* __restrict__ stats) {
  const int idx = blockIdx.x * 256 + threadIdx.x;
  if (blockIdx.x == 0) stats[threadIdx.x] = 0.f;
  float sa = 0.f, sc = 0.f, sy = 0.f;
#pragma unroll
  for (int s = 0; s < 4; ++s) {
    sa += P1[(s * 3 + 0) * (NN * HH) + idx];
    sc += P1[(s * 3 + 1) * (NN * HH) + idx];
    sy += P1[(s * 3 + 2) * (NN * HH) + idx];
  }
  const int h = idx & (HH - 1);
  aP[idx] = sa + b1[h];
  cP[idx] = sc;
  y[idx] = sy;
}

// ---------------------------------------------------------------------------
// K2: pairwise sim -> full symmetric adjacency A (diag = 1).
// Upper-triangle 32x32 tiles only; mirror written via LDS transpose.
// grid (32,32) with lower tiles early-exiting, block 256, 2x2 regs/thread.
// ---------------------------------------------------------------------------
__global__ __launch_bounds__(256) void k2_pairwise(
    const float* __restrict__ aP, const float* __restrict__ cP,
    const float* __restrict__ W2, const float* __restrict__ b2,
    float* __restrict__ A) {
  const int ti = blockIdx.x, tj = blockIdx.y;
  if (tj < ti) return;
  __shared__ float as[32 * 132];
  __shared__ float cs[32 * 132];
  __shared__ float es[32 * 33];
  const int tid = threadIdx.x;
  const int i0 = ti * 32, j0 = tj * 32;
  for (int idx = tid; idx < 32 * HH; idx += 256) {
    const int row = idx >> 7, col = idx & 127;
    as[row * 132 + col] = aP[(i0 + row) * HH + col];
    cs[row * 132 + col] = cP[(j0 + row) * HH + col];
  }
  __syncthreads();
  const int li0 = (tid >> 4) * 2, lj0 = (tid & 15) * 2;
  float s00 = 0.f, s01 = 0.f, s10 = 0.f, s11 = 0.f;
#pragma unroll 8
  for (int h = 0; h < HH; h += 4) {
    const float4 a0 = *(const float4*)(as + li0 * 132 + h);
    const float4 a1 = *(const float4*)(as + (li0 + 1) * 132 + h);
    const float4 c0 = *(const float4*)(cs + lj0 * 132 + h);
    const float4 c1 = *(const float4*)(cs + (lj0 + 1) * 132 + h);
    const float4 w = *(const float4*)(W2 + h);
    s00 += fmaxf(a0.x + c0.x, 0.f) * w.x + fmaxf(a0.y + c0.y, 0.f) * w.y +
           fmaxf(a0.z + c0.z, 0.f) * w.z + fmaxf(a0.w + c0.w, 0.f) * w.w;
    s01 += fmaxf(a0.x + c1.x, 0.f) * w.x + fmaxf(a0.y + c1.y, 0.f) * w.y +
           fmaxf(a0.z + c1.z, 0.f) * w.z + fmaxf(a0.w + c1.w, 0.f) * w.w;
    s10 += fmaxf(a1.x + c0.x, 0.f) * w.x + fmaxf(a1.y + c0.y, 0.f) * w.y +
           fmaxf(a1.z + c0.z, 0.f) * w.z + fmaxf(a1.w + c0.w, 0.f) * w.w;
    s11 += fmaxf(a1.x + c1.x, 0.f) * w.x + fmaxf(a1.y + c1.y, 0.f) * w.y +
           fmaxf(a1.z + c1.z, 0.f) * w.z + fmaxf(a1.w + c1.w, 0.f) * w.w;
  }
  const float b2v = b2[0];
  auto edge = [b2v](float s) {
    s += b2v;
    return s > 0.f ? 1.f / (1.f + __expf(-s)) : 0.f;  // sigmoid>0.5 <=> s>0
  };
  es[(li0 + 0) * 33 + lj0 + 0] = edge(s00);
  es[(li0 + 0) * 33 + lj0 + 1] = edge(s01);
  es[(li0 + 1) * 33 + lj0 + 0] = edge(s10);
  es[(li0 + 1) * 33 + lj0 + 1] = edge(s11);
  __syncthreads();
  if (ti == tj) {
#pragma unroll
    for (int r = 0; r < 2; ++r)
#pragma unroll
      for (int t = 0; t < 2; ++t) {
        const int li = li0 + r, lj = lj0 + t;
        const float v =
            (li == lj) ? 1.f : (li < lj ? es[li * 33 + lj] : es[lj * 33 + li]);
        A[(i0 + li) * NN + j0 + lj] = v;
      }
  } else {
#pragma unroll
    for (int r = 0; r < 2; ++r)
#pragma unroll
      for (int t = 0; t < 2; ++t) {
        const int li = li0 + r, lj = lj0 + t;
        A[(i0 + li) * NN + j0 + lj] = es[li * 33 + lj];
        A[(j0 + li) * NN + i0 + lj] = es[lj * 33 + li];  // mirror, coalesced
      }
  }
}

// ---------------------------------------------------------------------------
// K3: deg = row-sum of A; dis = rsqrt(deg); scale y row in place by dis[i].
// grid 1024 (one per row), block 256
// ---------------------------------------------------------------------------
__global__ __launch_bounds__(256) void k3_deg(
    const float* __restrict__ A, float* __restrict__ dis,
    float* __restrict__ y) {
  const int i = blockIdx.x;
  const int tid = threadIdx.x;
  const float4 v = *(const float4*)(A + i * NN + tid * 4);
  float s = v.x + v.y + v.z + v.w;
#pragma unroll
  for (int off = 32; off > 0; off >>= 1) s += __shfl_down(s, off, 64);
  __shared__ float sm[4];
  __shared__ float disb;
  if ((tid & 63) == 0) sm[tid >> 6] = s;
  __syncthreads();
  if (tid == 0) {
    const float tot = sm[0] + sm[1] + sm[2] + sm[3];
    const float dv = rsqrtf(tot);
    dis[i] = dv;
    disb = dv;
  }
  __syncthreads();
  if (tid < HH) y[i * HH + tid] *= disb;
}

// ---------------------------------------------------------------------------
// K4: partial out = A[:, jc:jc+128] @ Ys[jc:jc+128, :]   (split over j)
// grid (32 row-tiles, 8 j-chunks), block 256, 4 rows x 4 cols per thread.
// A tile staged transposed in LDS so the 4 row values come as one b128.
// ---------------------------------------------------------------------------
__global__ __launch_bounds__(256) void k4_spmm_partial(
    const float* __restrict__ A, const float* __restrict__ Ys,
    float* __restrict__ P4) {
  __shared__ float At[128 * 36];
  const int tid = threadIdx.x;
  const int i0 = blockIdx.x * 32;
  const int jc = blockIdx.y * 128;
  for (int idx = tid; idx < 32 * 128; idx += 256) {
    const int col = idx & 127, row = idx >> 7;
    At[col * 36 + row] = A[(i0 + row) * NN + jc + col];
  }
  __syncthreads();
  const int tx = tid & 31, ty = tid >> 5;
  float4 acc[4];
#pragma unroll
  for (int r = 0; r < 4; ++r) acc[r] = make_float4(0.f, 0.f, 0.f, 0.f);
  for (int jj = 0; jj < 128; ++jj) {
    const float4 av = *(const float4*)(At + jj * 36 + ty * 4);
    const float4 ys = *(const float4*)(Ys + (jc + jj) * HH + tx * 4);
    acc[0].x = fmaf(av.x, ys.x, acc[0].x); acc[0].y = fmaf(av.x, ys.y, acc[0].y);
    acc[0].z = fmaf(av.x, ys.z, acc[0].z); acc[0].w = fmaf(av.x, ys.w, acc[0].w);
    acc[1].x = fmaf(av.y, ys.x, acc[1].x); acc[1].y = fmaf(av.y, ys.y, acc[1].y);
    acc[1].z = fmaf(av.y, ys.z, acc[1].z); acc[1].w = fmaf(av.y, ys.w, acc[1].w);
    acc[2].x = fmaf(av.z, ys.x, acc[2].x); acc[2].y = fmaf(av.z, ys.y, acc[2].y);
    acc[2].z = fmaf(av.z, ys.z, acc[2].z); acc[2].w = fmaf(av.z, ys.w, acc[2].w);
    acc[3].x = fmaf(av.w, ys.x, acc[3].x); acc[3].y = fmaf(av.w, ys.y, acc[3].y);
    acc[3].z = fmaf(av.w, ys.z, acc[3].z); acc[3].w = fmaf(av.w, ys.w, acc[3].w);
  }
  const int bc = blockIdx.y;
#pragma unroll
  for (int r = 0; r < 4; ++r) {
    const int i = i0 + ty * 4 + r;
    *(float4*)(P4 + bc * (NN * HH) + i * HH + tx * 4) = acc[r];
  }
}

// ---------------------------------------------------------------------------
// K5a: reduce j-chunk partials, scale by dis[i], add bg; accumulate column
//      sum / sumsq via block-reduced atomics. grid 32, block 256.
// ---------------------------------------------------------------------------
__global__ __launch_bounds__(256) void k5a_reduce_stats(
    const float* __restrict__ P4, const float* __restrict__ dis,
    const float* __restrict__ bg, float* __restrict__ out_pre,
    float* __restrict__ stats) {
  const int tid = threadIdx.x;
  const int h = tid & 127, rg = tid >> 7;
  const int i0 = blockIdx.x * 32;
  float ls = 0.f, lq = 0.f;
  const float bgv = bg[h];
  for (int r = rg; r < 32; r += 2) {
    const int i = i0 + r;
    float v = 0.f;
#pragma unroll
    for (int s = 0; s < 8; ++s) v += P4[s * (NN * HH) + i * HH + h];
    v = v * dis[i] + bgv;
    out_pre[i * HH + h] = v;
    ls += v;
    lq += v * v;
  }
  __shared__ float sm1[2][128], sm2[2][128];
  sm1[rg][h] = ls;
  sm2[rg][h] = lq;
  __syncthreads();
  if (rg == 0) {
    atomicAdd(&stats[h], sm1[0][h] + sm1[1][h]);
    atomicAdd(&stats[128 + h], sm2[0][h] + sm2[1][h]);
  }
}

// ---------------------------------------------------------------------------
// K5b: BatchNorm (batch stats, biased var) + ReLU -> d_out. grid 512, blk 256
// ---------------------------------------------------------------------------
__global__ __launch_bounds__(256) void k5b_bn(
    const float* __restrict__ out_pre, const float* __restrict__ stats,
    const float* __restrict__ gamma, const float* __restrict__ beta,
    float* __restrict__ out) {
  const int idx = blockIdx.x * 256 + threadIdx.x;
  const int h = idx & 127;
  const float mean = stats[h] * (1.f / NN);
  const float var = stats[128 + h] * (1.f / NN) - mean * mean;
  float v = (out_pre[idx] - mean) * rsqrtf(var + BN_EPS);
  v = gamma[h] * v + beta[h];
  out[idx] = fmaxf(v, 0.f);
}

// ---------------------------------------------------------------------------
extern "C" void kernel_launch(void* const* d_in, const int* in_sizes, int n_in,
                              void* d_out, int out_size, void* d_ws,
                              size_t ws_size, hipStream_t stream) {
  const float* X = (const float*)d_in[0];
  const float* W1 = (const float*)d_in[1];
  const float* b1 = (const float*)d_in[2];
  const float* W2 = (const float*)d_in[3];
  const float* b2 = (const float*)d_in[4];
  const float* Wg = (const float*)d_in[5];
  const float* bg = (const float*)d_in[6];
  const float* gamma = (const float*)d_in[7];
  const float* beta = (const float*)d_in[8];
  float* out = (float*)d_out;

  float* w = (float*)d_ws;
  float* A = w + OFF_A;
  float* aP = w + OFF_AP;
  float* cP = w + OFF_CP;
  float* y = w + OFF_Y;
  float* dis = w + OFF_DIS;
  float* stats = w + OFF_STATS;
  float* out_pre = w + OFF_OUTPRE;
  float* P1 = w + OFF_P1;
  float* P4 = w + OFF_P4;

  k1_gemm_partial<<<dim3(32, 4), 256, 0, stream>>>(X, W1, Wg, P1);
  k1b_reduce<<<dim3(512), 256, 0, stream>>>(P1, b1, aP, cP, y, stats);
  k2_pairwise<<<dim3(32, 32), 256, 0, stream>>>(aP, cP, W2, b2, A);
  k3_deg<<<dim3(1024), 256, 0, stream>>>(A, dis, y);
  k4_spmm_partial<<<dim3(32, 8), 256, 0, stream>>>(A, y, P4);
  k5a_reduce_stats<<<dim3(32), 256, 0, stream>>>(P4, dis, bg, out_pre, stats);
  k5b_bn<<<dim3(512), 256, 0, stream>>>(out_pre, stats, gamma, beta, out);
}

// Round 2
// 121.198 us; speedup vs baseline: 1.3444x; 1.3444x over previous
//
#include <hip/hip_runtime.h>
#include <math.h>

// Problem constants
constexpr int NN = 1024;   // nodes
constexpr int DD = 256;    // embedding dim
constexpr int HH = 128;    // hidden dim
constexpr float BN_EPS = 1e-5f;

// Workspace layout (in floats)
constexpr int OFF_A      = 0;                          // [1024 x 1024] adjacency
constexpr int OFF_AP     = OFF_A + NN * NN;            // [N x H] a + b1
constexpr int OFF_CP     = OFF_AP + NN * HH;           // [N x H] c
constexpr int OFF_Y      = OFF_CP + NN * HH;           // [N x H] X@Wg
constexpr int OFF_DIS    = OFF_Y + NN * HH;            // [N] rsqrt(deg)
constexpr int OFF_STATS  = OFF_DIS + NN;               // [256] colsum, colsumsq
constexpr int OFF_OUTPRE = OFF_STATS + 256;            // [N x H] pre-BN output
constexpr int OFF_P4     = OFF_OUTPRE + NN * HH;       // [8 jchunks][N x H]

// ---------------------------------------------------------------------------
// K1: fused GEMMs  aP = X@W1[:D]+b1, cP = X@W1[D:], y = X@Wg.
// grid (64 row-tiles of 16, 3 matrices), block 256.
// X tile (full K) and W chunks both staged in LDS -> inner loop is LDS-only.
// ---------------------------------------------------------------------------
__global__ __launch_bounds__(256) void k1_gemm(
    const float* __restrict__ X, const float* __restrict__ W1,
    const float* __restrict__ Wg, const float* __restrict__ b1,
    float* __restrict__ aP, float* __restrict__ cP, float* __restrict__ y) {
  __shared__ float xs[16 * 256];   // 16 KB, [row][d] row-major
  __shared__ float ws[64 * 128];   // 32 KB, [d][h]
  const int tid = threadIdx.x;
  const int i0 = blockIdx.x * 16;
  const int m = blockIdx.y;
  const float* W = (m == 0) ? W1 : (m == 1 ? W1 + DD * HH : Wg);
  // Stage X tile: rows i0..i0+15 x all 256 d == contiguous 16 KB of X.
  const float* Xbase = X + i0 * DD;
#pragma unroll
  for (int v = 0; v < 4; ++v) {
    const int fi = (v * 256 + tid) * 4;
    *(float4*)(xs + fi) = *(const float4*)(Xbase + fi);
  }
  const int tx = tid & 31, ty = tid >> 5;  // cols tx*4..+3, rows ty*2..+1
  float4 acc0 = make_float4(0.f, 0.f, 0.f, 0.f);
  float4 acc1 = make_float4(0.f, 0.f, 0.f, 0.f);
  for (int c = 0; c < 4; ++c) {
    __syncthreads();  // xs ready (c=0) / previous ws reads done (c>0)
    const float* Wbase = W + c * 64 * HH;  // contiguous 32 KB chunk
#pragma unroll
    for (int v = 0; v < 8; ++v) {
      const int fi = (v * 256 + tid) * 4;
      *(float4*)(ws + fi) = *(const float4*)(Wbase + fi);
    }
    __syncthreads();
    const float* xr0 = xs + (ty * 2) * 256 + c * 64;
    const float* xr1 = xs + (ty * 2 + 1) * 256 + c * 64;
#pragma unroll 4
    for (int d = 0; d < 64; d += 4) {
      const float4 x0 = *(const float4*)(xr0 + d);
      const float4 x1 = *(const float4*)(xr1 + d);
      const float4 w0 = *(const float4*)(ws + (d + 0) * 128 + tx * 4);
      const float4 w1 = *(const float4*)(ws + (d + 1) * 128 + tx * 4);
      const float4 w2 = *(const float4*)(ws + (d + 2) * 128 + tx * 4);
      const float4 w3 = *(const float4*)(ws + (d + 3) * 128 + tx * 4);
      acc0.x = fmaf(x0.x, w0.x, acc0.x); acc0.y = fmaf(x0.x, w0.y, acc0.y);
      acc0.z = fmaf(x0.x, w0.z, acc0.z); acc0.w = fmaf(x0.x, w0.w, acc0.w);
      acc1.x = fmaf(x1.x, w0.x, acc1.x); acc1.y = fmaf(x1.x, w0.y, acc1.y);
      acc1.z = fmaf(x1.x, w0.z, acc1.z); acc1.w = fmaf(x1.x, w0.w, acc1.w);
      acc0.x = fmaf(x0.y, w1.x, acc0.x); acc0.y = fmaf(x0.y, w1.y, acc0.y);
      acc0.z = fmaf(x0.y, w1.z, acc0.z); acc0.w = fmaf(x0.y, w1.w, acc0.w);
      acc1.x = fmaf(x1.y, w1.x, acc1.x); acc1.y = fmaf(x1.y, w1.y, acc1.y);
      acc1.z = fmaf(x1.y, w1.z, acc1.z); acc1.w = fmaf(x1.y, w1.w, acc1.w);
      acc0.x = fmaf(x0.z, w2.x, acc0.x); acc0.y = fmaf(x0.z, w2.y, acc0.y);
      acc0.z = fmaf(x0.z, w2.z, acc0.z); acc0.w = fmaf(x0.z, w2.w, acc0.w);
      acc1.x = fmaf(x1.z, w2.x, acc1.x); acc1.y = fmaf(x1.z, w2.y, acc1.y);
      acc1.z = fmaf(x1.z, w2.z, acc1.z); acc1.w = fmaf(x1.z, w2.w, acc1.w);
      acc0.x = fmaf(x0.w, w3.x, acc0.x); acc0.y = fmaf(x0.w, w3.y, acc0.y);
      acc0.z = fmaf(x0.w, w3.z, acc0.z); acc0.w = fmaf(x0.w, w3.w, acc0.w);
      acc1.x = fmaf(x1.w, w3.x, acc1.x); acc1.y = fmaf(x1.w, w3.y, acc1.y);
      acc1.z = fmaf(x1.w, w3.z, acc1.z); acc1.w = fmaf(x1.w, w3.w, acc1.w);
    }
  }
  float* dst = (m == 0) ? aP : (m == 1 ? cP : y);
  if (m == 0) {
    const float4 bv = *(const float4*)(b1 + tx * 4);
    acc0.x += bv.x; acc0.y += bv.y; acc0.z += bv.z; acc0.w += bv.w;
    acc1.x += bv.x; acc1.y += bv.y; acc1.z += bv.z; acc1.w += bv.w;
  }
  const int r0 = i0 + ty * 2;
  *(float4*)(dst + r0 * HH + tx * 4) = acc0;
  *(float4*)(dst + (r0 + 1) * HH + tx * 4) = acc1;
}

// ---------------------------------------------------------------------------
// K2: pairwise sim -> full symmetric adjacency A (diag = 1).
// Upper-triangle 32x32 tiles only; mirror written via LDS transpose.
// ---------------------------------------------------------------------------
__global__ __launch_bounds__(256) void k2_pairwise(
    const float* __restrict__ aP, const float* __restrict__ cP,
    const float* __restrict__ W2, const float* __restrict__ b2,
    float* __restrict__ A) {
  const int ti = blockIdx.x, tj = blockIdx.y;
  if (tj < ti) return;
  __shared__ float as[32 * 132];
  __shared__ float cs[32 * 132];
  __shared__ float es[32 * 33];
  const int tid = threadIdx.x;
  const int i0 = ti * 32, j0 = tj * 32;
  for (int idx = tid; idx < 32 * HH; idx += 256) {
    const int row = idx >> 7, col = idx & 127;
    as[row * 132 + col] = aP[(i0 + row) * HH + col];
    cs[row * 132 + col] = cP[(j0 + row) * HH + col];
  }
  __syncthreads();
  const int li0 = (tid >> 4) * 2, lj0 = (tid & 15) * 2;
  float s00 = 0.f, s01 = 0.f, s10 = 0.f, s11 = 0.f;
#pragma unroll 8
  for (int h = 0; h < HH; h += 4) {
    const float4 a0 = *(const float4*)(as + li0 * 132 + h);
    const float4 a1 = *(const float4*)(as + (li0 + 1) * 132 + h);
    const float4 c0 = *(const float4*)(cs + lj0 * 132 + h);
    const float4 c1 = *(const float4*)(cs + (lj0 + 1) * 132 + h);
    const float4 w = *(const float4*)(W2 + h);
    s00 += fmaxf(a0.x + c0.x, 0.f) * w.x + fmaxf(a0.y + c0.y, 0.f) * w.y +
           fmaxf(a0.z + c0.z, 0.f) * w.z + fmaxf(a0.w + c0.w, 0.f) * w.w;
    s01 += fmaxf(a0.x + c1.x, 0.f) * w.x + fmaxf(a0.y + c1.y, 0.f) * w.y +
           fmaxf(a0.z + c1.z, 0.f) * w.z + fmaxf(a0.w + c1.w, 0.f) * w.w;
    s10 += fmaxf(a1.x + c0.x, 0.f) * w.x + fmaxf(a1.y + c0.y, 0.f) * w.y +
           fmaxf(a1.z + c0.z, 0.f) * w.z + fmaxf(a1.w + c0.w, 0.f) * w.w;
    s11 += fmaxf(a1.x + c1.x, 0.f) * w.x + fmaxf(a1.y + c1.y, 0.f) * w.y +
           fmaxf(a1.z + c1.z, 0.f) * w.z + fmaxf(a1.w + c1.w, 0.f) * w.w;
  }
  const float b2v = b2[0];
  auto edge = [b2v](float s) {
    s += b2v;
    return s > 0.f ? 1.f / (1.f + __expf(-s)) : 0.f;  // sigmoid>0.5 <=> s>0
  };
  es[(li0 + 0) * 33 + lj0 + 0] = edge(s00);
  es[(li0 + 0) * 33 + lj0 + 1] = edge(s01);
  es[(li0 + 1) * 33 + lj0 + 0] = edge(s10);
  es[(li0 + 1) * 33 + lj0 + 1] = edge(s11);
  __syncthreads();
  if (ti == tj) {
#pragma unroll
    for (int r = 0; r < 2; ++r)
#pragma unroll
      for (int t = 0; t < 2; ++t) {
        const int li = li0 + r, lj = lj0 + t;
        const float v =
            (li == lj) ? 1.f : (li < lj ? es[li * 33 + lj] : es[lj * 33 + li]);
        A[(i0 + li) * NN + j0 + lj] = v;
      }
  } else {
#pragma unroll
    for (int r = 0; r < 2; ++r)
#pragma unroll
      for (int t = 0; t < 2; ++t) {
        const int li = li0 + r, lj = lj0 + t;
        A[(i0 + li) * NN + j0 + lj] = es[li * 33 + lj];
        A[(j0 + li) * NN + i0 + lj] = es[lj * 33 + li];  // mirror, coalesced
      }
  }
}

// ---------------------------------------------------------------------------
// K3: dis = rsqrt(rowsum(A)); block 0 also zero-inits BN stats accumulators.
// grid 1024, block 256
// ---------------------------------------------------------------------------
__global__ __launch_bounds__(256) void k3_deg(
    const float* __restrict__ A, float* __restrict__ dis,
    float* __restrict__ stats) {
  const int i = blockIdx.x;
  const int tid = threadIdx.x;
  if (i == 0) stats[tid] = 0.f;
  const float4 v = *(const float4*)(A + i * NN + tid * 4);
  float s = v.x + v.y + v.z + v.w;
#pragma unroll
  for (int off = 32; off > 0; off >>= 1) s += __shfl_down(s, off, 64);
  __shared__ float sm[4];
  if ((tid & 63) == 0) sm[tid >> 6] = s;
  __syncthreads();
  if (tid == 0) dis[i] = rsqrtf(sm[0] + sm[1] + sm[2] + sm[3]);
}

// ---------------------------------------------------------------------------
// K4: partial out = A[:, jc:jc+128] @ (dis[j] * Y[j,:])   (split over j)
// grid (32 row-tiles, 8 j-chunks), block 256, 4 rows x 4 cols per thread.
// Both A (transposed) and Y sub-chunks staged in LDS -> inner loop LDS-only.
// ---------------------------------------------------------------------------
__global__ __launch_bounds__(256) void k4_spmm_partial(
    const float* __restrict__ A, const float* __restrict__ Y,
    const float* __restrict__ dis, float* __restrict__ P4) {
  __shared__ float At[128 * 36];   // 18 KB, [col][row]
  __shared__ float ys[32 * 128];   // 16 KB, [j][h], dis-scaled
  const int tid = threadIdx.x;
  const int i0 = blockIdx.x * 32;
  const int jc = blockIdx.y * 128;
  for (int idx = tid; idx < 32 * 128; idx += 256) {
    const int col = idx & 127, row = idx >> 7;
    At[col * 36 + row] = A[(i0 + row) * NN + jc + col];
  }
  const int tx = tid & 31, ty = tid >> 5;
  float4 acc[4];
#pragma unroll
  for (int r = 0; r < 4; ++r) acc[r] = make_float4(0.f, 0.f, 0.f, 0.f);
  for (int s = 0; s < 4; ++s) {
    __syncthreads();
#pragma unroll
    for (int v = 0; v < 4; ++v) {
      const int fi = (v * 256 + tid) * 4;
      const int r = fi >> 7, col = fi & 127;
      float4 t = *(const float4*)(Y + (jc + s * 32 + r) * HH + col);
      const float dv = dis[jc + s * 32 + r];
      t.x *= dv; t.y *= dv; t.z *= dv; t.w *= dv;
      *(float4*)(ys + fi) = t;
    }
    __syncthreads();
#pragma unroll 8
    for (int jj = 0; jj < 32; ++jj) {
      const float4 av = *(const float4*)(At + (s * 32 + jj) * 36 + ty * 4);
      const float4 yv = *(const float4*)(ys + jj * 128 + tx * 4);
      acc[0].x = fmaf(av.x, yv.x, acc[0].x); acc[0].y = fmaf(av.x, yv.y, acc[0].y);
      acc[0].z = fmaf(av.x, yv.z, acc[0].z); acc[0].w = fmaf(av.x, yv.w, acc[0].w);
      acc[1].x = fmaf(av.y, yv.x, acc[1].x); acc[1].y = fmaf(av.y, yv.y, acc[1].y);
      acc[1].z = fmaf(av.y, yv.z, acc[1].z); acc[1].w = fmaf(av.y, yv.w, acc[1].w);
      acc[2].x = fmaf(av.z, yv.x, acc[2].x); acc[2].y = fmaf(av.z, yv.y, acc[2].y);
      acc[2].z = fmaf(av.z, yv.z, acc[2].z); acc[2].w = fmaf(av.z, yv.w, acc[2].w);
      acc[3].x = fmaf(av.w, yv.x, acc[3].x); acc[3].y = fmaf(av.w, yv.y, acc[3].y);
      acc[3].z = fmaf(av.w, yv.z, acc[3].z); acc[3].w = fmaf(av.w, yv.w, acc[3].w);
    }
  }
  const int bc = blockIdx.y;
#pragma unroll
  for (int r = 0; r < 4; ++r) {
    const int i = i0 + ty * 4 + r;
    *(float4*)(P4 + bc * (NN * HH) + i * HH + tx * 4) = acc[r];
  }
}

// ---------------------------------------------------------------------------
// K5a: reduce j-chunk partials, scale by dis[i], add bg; accumulate column
//      sum / sumsq via block-reduced atomics. grid 128 (8 rows each), blk 256.
// ---------------------------------------------------------------------------
__global__ __launch_bounds__(256) void k5a_reduce_stats(
    const float* __restrict__ P4, const float* __restrict__ dis,
    const float* __restrict__ bg, float* __restrict__ out_pre,
    float* __restrict__ stats) {
  const int tid = threadIdx.x;
  const int h = tid & 127, rg = tid >> 7;
  const int i0 = blockIdx.x * 8;
  float ls = 0.f, lq = 0.f;
  const float bgv = bg[h];
#pragma unroll
  for (int r = rg; r < 8; r += 2) {
    const int i = i0 + r;
    float v = 0.f;
#pragma unroll
    for (int s = 0; s < 8; ++s) v += P4[s * (NN * HH) + i * HH + h];
    v = v * dis[i] + bgv;
    out_pre[i * HH + h] = v;
    ls += v;
    lq += v * v;
  }
  __shared__ float sm1[2][128], sm2[2][128];
  sm1[rg][h] = ls;
  sm2[rg][h] = lq;
  __syncthreads();
  if (rg == 0) {
    atomicAdd(&stats[h], sm1[0][h] + sm1[1][h]);
    atomicAdd(&stats[128 + h], sm2[0][h] + sm2[1][h]);
  }
}

// ---------------------------------------------------------------------------
// K5b: BatchNorm (batch stats, biased var) + ReLU -> d_out. grid 512, blk 256
// ---------------------------------------------------------------------------
__global__ __launch_bounds__(256) void k5b_bn(
    const float* __restrict__ out_pre, const float* __restrict__ stats,
    const float* __restrict__ gamma, const float* __restrict__ beta,
    float* __restrict__ out) {
  const int idx = blockIdx.x * 256 + threadIdx.x;
  const int h = idx & 127;
  const float mean = stats[h] * (1.f / NN);
  const float var = stats[128 + h] * (1.f / NN) - mean * mean;
  float v = (out_pre[idx] - mean) * rsqrtf(var + BN_EPS);
  v = gamma[h] * v + beta[h];
  out[idx] = fmaxf(v, 0.f);
}

// ---------------------------------------------------------------------------
extern "C" void kernel_launch(void* const* d_in, const int* in_sizes, int n_in,
                              void* d_out, int out_size, void* d_ws,
                              size_t ws_size, hipStream_t stream) {
  const float* X = (const float*)d_in[0];
  const float* W1 = (const float*)d_in[1];
  const float* b1 = (const float*)d_in[2];
  const float* W2 = (const float*)d_in[3];
  const float* b2 = (const float*)d_in[4];
  const float* Wg = (const float*)d_in[5];
  const float* bg = (const float*)d_in[6];
  const float* gamma = (const float*)d_in[7];
  const float* beta = (const float*)d_in[8];
  float* out = (float*)d_out;

  float* w = (float*)d_ws;
  float* A = w + OFF_A;
  float* aP = w + OFF_AP;
  float* cP = w + OFF_CP;
  float* y = w + OFF_Y;
  float* dis = w + OFF_DIS;
  float* stats = w + OFF_STATS;
  float* out_pre = w + OFF_OUTPRE;
  float* P4 = w + OFF_P4;

  k1_gemm<<<dim3(64, 3), 256, 0, stream>>>(X, W1, Wg, b1, aP, cP, y);
  k2_pairwise<<<dim3(32, 32), 256, 0, stream>>>(aP, cP, W2, b2, A);
  k3_deg<<<dim3(1024), 256, 0, stream>>>(A, dis, stats);
  k4_spmm_partial<<<dim3(32, 8), 256, 0, stream>>>(A, y, dis, P4);
  k5a_reduce_stats<<<dim3(128), 256, 0, stream>>>(P4, dis, bg, out_pre, stats);
  k5b_bn<<<dim3(512), 256, 0, stream>>>(out_pre, stats, gamma, beta, out);
}